// Round 2
// baseline (1072.723 us; speedup 1.0000x reference)
//
#include <hip/hip_runtime.h>

typedef short s16x8 __attribute__((ext_vector_type(8)));
typedef float f32x4 __attribute__((ext_vector_type(4)));

constexpr int BATCH = 32, NODES = 512, DIM = 768, LAYERS = 4;
constexpr float QK_SCALE = 0.03608439182435161f;  // 1/sqrt(768)

constexpr size_t OUT_OFF  = 0;
constexpr size_t RET_OFF  = (size_t)BATCH * NODES * DIM;                       // 12582912
constexpr size_t ADJS_OFF = RET_OFF + (size_t)BATCH * NODES * (LAYERS + 1);    // 12664832
constexpr size_t L0_OFF   = ADJS_OFF + (size_t)BATCH * NODES * NODES * LAYERS; // 46219264
constexpr size_t C_OFF    = L0_OFF + 1;
constexpr size_t G_OFF    = C_OFF + BATCH * LAYERS;

#define DEVI static __device__ __forceinline__

DEVI float bf2f(unsigned short u) {
    union { unsigned int i; float f; } v; v.i = ((unsigned int)u) << 16; return v.f;
}
DEVI unsigned short f2bf(float f) {
    union { float f; unsigned int i; } v; v.f = f;
    return (unsigned short)((v.i + 0x7FFFu + ((v.i >> 16) & 1u)) >> 16);
}
DEVI ushort4 pk4(float4 v) {
    ushort4 o; o.x = f2bf(v.x); o.y = f2bf(v.y); o.z = f2bf(v.z); o.w = f2bf(v.w); return o;
}
DEVI float sigm(float x) { return 1.0f / (1.0f + __expf(-x)); }

// ---------------------------------------------------------------------------
// Generic NT GEMM: C[m,n] = sum_k A[m,k] * B[n,k]   (acc f32, MFMA bf16)
// A is f32 (AF32=true, converted during staging) or bf16. B is always bf16.
// MODE 0: proj (z selects Wq^T/Wk^T, C = q or k, bf16 store)
// MODE 1: scores (epilogue: adj = sigmoid(S*scale)*pm_n*pm_m; writes adjs
//         interleaved f32 output + adj^T bf16 ws; accumulates deg/l0/c/g)
// MODE 2: aggregation (epilogue: *= dis[row], bf16 store)
// ---------------------------------------------------------------------------
template <int MODE, bool AF32>
__global__ __launch_bounds__(256) void gemm_nt(
    const void* __restrict__ A0v, const unsigned short* __restrict__ Bq,
    const unsigned short* __restrict__ Bk, unsigned short* __restrict__ C0,
    int K, int lda, int ldb, int ldc,
    long sA, long sB, long sC,
    const float* __restrict__ pmask, float* __restrict__ deg,
    unsigned short* __restrict__ adjT, float* __restrict__ adjs_out,
    float* __restrict__ l0_acc, float* __restrict__ c_acc, float* __restrict__ g_acc,
    const float* __restrict__ dis, int layer)
{
    __shared__ __align__(16) unsigned short As[128 * 40];
    __shared__ __align__(16) unsigned short Bs[128 * 40];
    __shared__ float pmr[128];
    __shared__ float pmc[128];

    const int tid  = threadIdx.x;
    const int lane = tid & 63;
    const int wave = tid >> 6;
    const int wr = (wave >> 1) << 6;
    const int wc = (wave & 1) << 6;
    const int z = blockIdx.z;
    const int rows0 = blockIdx.x << 7;
    const int cols0 = blockIdx.y << 7;

    const size_t aoff = (size_t)z * sA + (size_t)rows0 * lda;
    const float* Af = (const float*)A0v + aoff;
    const unsigned short* Ab = (const unsigned short*)A0v + aoff;
    const unsigned short* Bsrc = ((MODE == 0 && z == 1) ? Bk : Bq) + (size_t)z * sB + (size_t)cols0 * ldb;

    f32x4 acc[4][4] = {};

    const int lrow = tid >> 2;          // 0..63
    const int lkc  = (tid & 3) << 3;    // 0,8,16,24 (elements)
    const int mrow = lane & 15;
    const int kq   = (lane >> 4) << 3;

    for (int kt = 0; kt < K; kt += 32) {
        __syncthreads();
        uint4 vb0 = *(const uint4*)(Bsrc + (size_t)lrow * ldb + kt + lkc);
        uint4 vb1 = *(const uint4*)(Bsrc + (size_t)(lrow + 64) * ldb + kt + lkc);
        if constexpr (AF32) {
            float4 a0 = *(const float4*)(Af + (size_t)lrow * lda + kt + lkc);
            float4 a1 = *(const float4*)(Af + (size_t)lrow * lda + kt + lkc + 4);
            float4 a2 = *(const float4*)(Af + (size_t)(lrow + 64) * lda + kt + lkc);
            float4 a3 = *(const float4*)(Af + (size_t)(lrow + 64) * lda + kt + lkc + 4);
            *(ushort4*)(&As[lrow * 40 + lkc])            = pk4(a0);
            *(ushort4*)(&As[lrow * 40 + lkc + 4])        = pk4(a1);
            *(ushort4*)(&As[(lrow + 64) * 40 + lkc])     = pk4(a2);
            *(ushort4*)(&As[(lrow + 64) * 40 + lkc + 4]) = pk4(a3);
        } else {
            uint4 va0 = *(const uint4*)(Ab + (size_t)lrow * lda + kt + lkc);
            uint4 va1 = *(const uint4*)(Ab + (size_t)(lrow + 64) * lda + kt + lkc);
            *(uint4*)(&As[lrow * 40 + lkc]) = va0;
            *(uint4*)(&As[(lrow + 64) * 40 + lkc]) = va1;
        }
        *(uint4*)(&Bs[lrow * 40 + lkc]) = vb0;
        *(uint4*)(&Bs[(lrow + 64) * 40 + lkc]) = vb1;
        __syncthreads();

        s16x8 af[4], bfr[4];
        #pragma unroll
        for (int i = 0; i < 4; ++i) {
            af[i]  = *(const s16x8*)(&As[(wr + i * 16 + mrow) * 40 + kq]);
            bfr[i] = *(const s16x8*)(&Bs[(wc + i * 16 + mrow) * 40 + kq]);
        }
        #pragma unroll
        for (int i = 0; i < 4; ++i)
            #pragma unroll
            for (int j = 0; j < 4; ++j)
                acc[i][j] = __builtin_amdgcn_mfma_f32_16x16x32_bf16(af[i], bfr[j], acc[i][j], 0, 0, 0);
    }

    const int colb = lane & 15, quad = lane >> 4;

    if constexpr (MODE != 1) {
        unsigned short* C = C0 + (size_t)z * sC;
        #pragma unroll
        for (int i = 0; i < 4; ++i) {
            const int rbase = rows0 + wr + i * 16 + (quad << 2);
            float dv[4];
            if constexpr (MODE == 2) {
                #pragma unroll
                for (int r = 0; r < 4; ++r) dv[r] = dis[(size_t)z * NODES + rbase + r];
            }
            #pragma unroll
            for (int j = 0; j < 4; ++j) {
                const int cc = cols0 + wc + j * 16 + colb;
                #pragma unroll
                for (int r = 0; r < 4; ++r) {
                    float v = acc[i][j][r];
                    if constexpr (MODE == 2) v *= dv[r];
                    C[(size_t)(rbase + r) * ldc + cc] = f2bf(v);
                }
            }
        }
    } else {
        __syncthreads();
        if (tid < 128) pmr[tid] = pmask[(size_t)z * NODES + rows0 + tid];
        else if (tid < 256) pmc[tid - 128] = pmask[(size_t)z * NODES + cols0 + (tid - 128)];
        __syncthreads();

        float tot = 0.f, gs = 0.f, cs = 0.f;
        #pragma unroll
        for (int i = 0; i < 4; ++i) {
            const int nloc = wr + i * 16 + (quad << 2);
            #pragma unroll
            for (int r = 0; r < 4; ++r) {
                const int n = rows0 + nloc + r;
                const float pmn = pmr[nloc + r];
                float dp = 0.f;
                #pragma unroll
                for (int j = 0; j < 4; ++j) {
                    const int mloc = wc + j * 16 + colb;
                    const int m = cols0 + mloc;
                    float a = pmn * pmc[mloc] * sigm(acc[i][j][r] * QK_SCALE);
                    acc[i][j][r] = a;
                    dp += a;
                    tot += a;
                    if (m < NODES - 1) {
                        if (n < NODES - 1) gs += a;
                        else cs += a;
                    }
                    adjs_out[(((size_t)z * NODES + n) * NODES + m) * LAYERS + layer] = a;
                }
                dp += __shfl_xor(dp, 1, 16);
                dp += __shfl_xor(dp, 2, 16);
                dp += __shfl_xor(dp, 4, 16);
                dp += __shfl_xor(dp, 8, 16);
                if (colb == 0) atomicAdd(&deg[(size_t)z * NODES + n], dp);
            }
        }
        // adj^T (bf16, [b][m][n]) for the aggregation GEMM: 4 consecutive n per lane
        #pragma unroll
        for (int i = 0; i < 4; ++i) {
            const int nb = rows0 + wr + i * 16 + (quad << 2);
            #pragma unroll
            for (int j = 0; j < 4; ++j) {
                const int m = cols0 + wc + j * 16 + colb;
                ushort4 pk;
                pk.x = f2bf(acc[i][j][0]); pk.y = f2bf(acc[i][j][1]);
                pk.z = f2bf(acc[i][j][2]); pk.w = f2bf(acc[i][j][3]);
                *(ushort4*)(adjT + ((size_t)z * NODES + m) * NODES + nb) = pk;
            }
        }
        #pragma unroll
        for (int o = 1; o < 64; o <<= 1) {
            tot += __shfl_xor(tot, o, 64);
            gs  += __shfl_xor(gs, o, 64);
            cs  += __shfl_xor(cs, o, 64);
        }
        if (lane == 0) {
            atomicAdd(l0_acc, tot);
            atomicAdd(&g_acc[z * LAYERS + layer], gs);
            atomicAdd(&c_acc[z * LAYERS + layer], cs);
        }
    }
}

// ---------------------------------------------------------------------------
// W^T: Wt[l][n][k] = bf16(W[l][k][n])  (768x768 f32 -> bf16), z = which*4 + l
// ---------------------------------------------------------------------------
__global__ void transpose_w(const float* __restrict__ Wq, const float* __restrict__ Wk,
                            unsigned short* __restrict__ Wqt, unsigned short* __restrict__ Wkt)
{
    __shared__ unsigned short t[32][36];
    const int which = blockIdx.z >> 2, l = blockIdx.z & 3;
    const float* src = (which ? Wk : Wq) + (size_t)l * DIM * DIM;
    unsigned short* dst = (which ? Wkt : Wqt) + (size_t)l * DIM * DIM;
    const int r0 = blockIdx.x << 5, c0 = blockIdx.y << 5;
    const int tr = threadIdx.x >> 3, tc = (threadIdx.x & 7) << 2;
    float4 v = *(const float4*)(src + (size_t)(r0 + tr) * DIM + c0 + tc);
    t[tr][tc] = f2bf(v.x); t[tr][tc + 1] = f2bf(v.y);
    t[tr][tc + 2] = f2bf(v.z); t[tr][tc + 3] = f2bf(v.w);
    __syncthreads();
    ushort4 o;
    o.x = t[tc + 0][tr]; o.y = t[tc + 1][tr]; o.z = t[tc + 2][tr]; o.w = t[tc + 3][tr];
    *(ushort4*)(dst + (size_t)(c0 + tr) * DIM + r0 + tc) = o;
}

// ---------------------------------------------------------------------------
// fp_t[b][d][n] = bf16(dis[b][n] * X[b][n][d])   (X f32 or bf16)
// ---------------------------------------------------------------------------
template <bool XF32>
__global__ void fp_transpose(const void* __restrict__ Xv, const float* __restrict__ dis,
                             unsigned short* __restrict__ fpt)
{
    __shared__ unsigned short t[32][36];
    const int b = blockIdx.z;
    const int n0 = blockIdx.x << 5, d0 = blockIdx.y << 5;
    const int tr = threadIdx.x >> 3, tc = (threadIdx.x & 7) << 2;
    const float dv = dis[(size_t)b * NODES + n0 + tr];
    float x0, x1, x2, x3;
    if constexpr (XF32) {
        float4 v = *(const float4*)((const float*)Xv + ((size_t)b * NODES + n0 + tr) * DIM + d0 + tc);
        x0 = v.x; x1 = v.y; x2 = v.z; x3 = v.w;
    } else {
        ushort4 v = *(const ushort4*)((const unsigned short*)Xv + ((size_t)b * NODES + n0 + tr) * DIM + d0 + tc);
        x0 = bf2f(v.x); x1 = bf2f(v.y); x2 = bf2f(v.z); x3 = bf2f(v.w);
    }
    t[tr][tc]     = f2bf(x0 * dv);
    t[tr][tc + 1] = f2bf(x1 * dv);
    t[tr][tc + 2] = f2bf(x2 * dv);
    t[tr][tc + 3] = f2bf(x3 * dv);
    __syncthreads();
    ushort4 o;
    o.x = t[tc + 0][tr]; o.y = t[tc + 1][tr]; o.z = t[tc + 2][tr]; o.w = t[tc + 3][tr];
    *(ushort4*)(fpt + ((size_t)b * DIM + d0 + tr) * NODES + n0 + tc) = o;
}

__global__ void dis_kernel(const float* __restrict__ deg, float* __restrict__ dis)
{
    const int i = blockIdx.x * 256 + threadIdx.x;
    const float d = deg[i];
    dis[i] = d > 0.f ? rsqrtf(fmaxf(d, 1e-12f)) : 0.f;
}

__global__ void psum_kernel(const float* __restrict__ pm, float* __restrict__ ps)
{
    const int b = blockIdx.x, t = threadIdx.x;
    float s = pm[(size_t)b * NODES + t] + pm[(size_t)b * NODES + 256 + t];
    #pragma unroll
    for (int o = 1; o < 64; o <<= 1) s += __shfl_xor(s, o, 64);
    __shared__ float sh[4];
    if ((t & 63) == 0) sh[t >> 6] = s;
    __syncthreads();
    if (t == 0) ps[b] = sh[0] + sh[1] + sh[2] + sh[3];
}

// ---------------------------------------------------------------------------
// Attention-pool epilogue per pred: r = sigmoid(X·w + b); retain[:,:,lp] = r;
// mode 0: acc = r*X    mode 1: acc += r*X    mode 2: out = f32(acc + r*X)
// One wave per (b,n) row. X is f32 (pred 0) or bf16 (later preds).
// ---------------------------------------------------------------------------
template <bool XF32>
__global__ __launch_bounds__(256) void pool_kernel(
    const void* __restrict__ Xv, const float* __restrict__ pw,
    const float* __restrict__ pb, float* __restrict__ ret,
    float* __restrict__ acc, float* __restrict__ outb, int lp, int mode)
{
    const int row = (blockIdx.x << 2) + (threadIdx.x >> 6);
    const int lane = threadIdx.x & 63;
    float xs[12];
    float dot = 0.f;
    #pragma unroll
    for (int c = 0; c < 3; ++c) {
        const int idx = c * 256 + (lane << 2);
        float4 wv = *(const float4*)(pw + idx);
        float a0, a1, a2, a3;
        if constexpr (XF32) {
            float4 xv = *(const float4*)((const float*)Xv + (size_t)row * DIM + idx);
            a0 = xv.x; a1 = xv.y; a2 = xv.z; a3 = xv.w;
        } else {
            ushort4 xv = *(const ushort4*)((const unsigned short*)Xv + (size_t)row * DIM + idx);
            a0 = bf2f(xv.x); a1 = bf2f(xv.y); a2 = bf2f(xv.z); a3 = bf2f(xv.w);
        }
        xs[c * 4 + 0] = a0; xs[c * 4 + 1] = a1; xs[c * 4 + 2] = a2; xs[c * 4 + 3] = a3;
        dot += a0 * wv.x + a1 * wv.y + a2 * wv.z + a3 * wv.w;
    }
    #pragma unroll
    for (int o = 1; o < 64; o <<= 1) dot += __shfl_xor(dot, o, 64);
    const float r = sigm(dot + pb[0]);
    if (lane == 0) ret[(size_t)row * (LAYERS + 1) + lp] = r;
    float* ar = acc + (size_t)row * DIM;
    float* orow = outb + (size_t)row * DIM;
    #pragma unroll
    for (int c = 0; c < 3; ++c) {
        const int idx = c * 256 + (lane << 2);
        float a0 = r * xs[c * 4 + 0], a1 = r * xs[c * 4 + 1];
        float a2 = r * xs[c * 4 + 2], a3 = r * xs[c * 4 + 3];
        if (mode != 0) {
            float4 p = *(const float4*)(ar + idx);
            a0 += p.x; a1 += p.y; a2 += p.z; a3 += p.w;
        }
        float4 p; p.x = a0; p.y = a1; p.z = a2; p.w = a3;
        if (mode == 2) *(float4*)(orow + idx) = p;
        else           *(float4*)(ar + idx) = p;
    }
}

__global__ void finalize_kernel(const float* __restrict__ ps, const float* __restrict__ c_acc,
                                const float* __restrict__ g_acc, const float* __restrict__ l0,
                                float* __restrict__ ob)
{
    const int t = threadIdx.x;
    if (t < BATCH * LAYERS) {
        const int b = t >> 2;
        const float p = ps[b];
        ob[C_OFF + t] = c_acc[t] / p;
        ob[G_OFF + t] = g_acc[t] / (p * p);
    }
    if (t == 0) {
        float fs = 1e-8f;
        for (int b = 0; b < BATCH; ++b) fs += ps[b] * ps[b];
        ob[L0_OFF] = l0[0] / (fs * (float)LAYERS);
    }
}

// ---------------------------------------------------------------------------
extern "C" void kernel_launch(void* const* d_in, const int* in_sizes, int n_in,
                              void* d_out, int out_size, void* d_ws, size_t ws_size,
                              hipStream_t stream)
{
    (void)in_sizes; (void)n_in; (void)out_size; (void)ws_size;
    const float* pmask = (const float*)d_in[0];
    const float* feat  = (const float*)d_in[1];
    const float* Wq    = (const float*)d_in[2];
    const float* Wk    = (const float*)d_in[3];
    const float* projw = (const float*)d_in[4];
    const float* projb = (const float*)d_in[5];
    float* ob = (float*)d_out;

    char* w = (char*)d_ws;
    unsigned short* Xws  = (unsigned short*)(w + 0);          //  25165824 B  bf16 [B,N,D]
    unsigned short* qws  = (unsigned short*)(w + 25165824);   //  25165824 B  bf16 q / fp_t (reused)
    unsigned short* kws  = (unsigned short*)(w + 50331648);   //  25165824 B  bf16 k
    unsigned short* adjT = (unsigned short*)(w + 75497472);   //  16777216 B  bf16 [B,N(m),N(n)]
    unsigned short* Wqt  = (unsigned short*)(w + 92274688);   //   4718592 B  bf16
    unsigned short* Wkt  = (unsigned short*)(w + 96993280);   //   4718592 B  bf16
    float* out_acc = (float*)(w + 101711872);                 //  50331648 B  f32 [B,N,D]
    float* deg_all = (float*)(w + 152043520);                 //    262144 B  f32 [L,B,N]
    float* c_acc   = (float*)(w + 152305664);                 //       512 B
    float* g_acc   = (float*)(w + 152306176);                 //       512 B
    float* l0_acc  = (float*)(w + 152306688);                 //       256 B
    float* disws   = (float*)(w + 152306944);                 //     65536 B  f32 [B,N]
    float* p_sum   = (float*)(w + 152372480);                 //       256 B

    dim3 blk(256);
    hipMemsetAsync(w + 152043520, 0, 263424, stream);  // deg_all + c_acc + g_acc + l0_acc

    transpose_w<<<dim3(24, 24, 8), blk, 0, stream>>>(Wq, Wk, Wqt, Wkt);
    psum_kernel<<<dim3(32), blk, 0, stream>>>(pmask, p_sum);
    pool_kernel<true><<<dim3(4096), blk, 0, stream>>>(feat, projw, projb, ob + RET_OFF, out_acc, ob + OUT_OFF, 0, 0);

    for (int l = 0; l < LAYERS; ++l) {
        float* deg_l = deg_all + (size_t)l * BATCH * NODES;

        // q = X @ Wq[l], k = X @ Wk[l]  (z selects q/k; C z-stride lands on kws)
        if (l == 0) {
            gemm_nt<0, true><<<dim3(128, 6, 2), blk, 0, stream>>>(
                feat, Wqt + (size_t)l * DIM * DIM, Wkt + (size_t)l * DIM * DIM, qws,
                DIM, DIM, DIM, DIM, 0L, 0L, (long)BATCH * NODES * DIM,
                nullptr, nullptr, nullptr, nullptr, nullptr, nullptr, nullptr, nullptr, 0);
        } else {
            gemm_nt<0, false><<<dim3(128, 6, 2), blk, 0, stream>>>(
                Xws, Wqt + (size_t)l * DIM * DIM, Wkt + (size_t)l * DIM * DIM, qws,
                DIM, DIM, DIM, DIM, 0L, 0L, (long)BATCH * NODES * DIM,
                nullptr, nullptr, nullptr, nullptr, nullptr, nullptr, nullptr, nullptr, 0);
        }

        // S = q @ k^T (batched) + sigmoid/mask epilogue
        gemm_nt<1, false><<<dim3(4, 4, 32), blk, 0, stream>>>(
            qws, kws, nullptr, nullptr,
            DIM, DIM, DIM, 0, (long)NODES * DIM, (long)NODES * DIM, 0L,
            pmask, deg_l, adjT, ob + ADJS_OFF, l0_acc, c_acc, g_acc, nullptr, l);

        dis_kernel<<<dim3(64), blk, 0, stream>>>(deg_l, disws);
        if (l == 0) fp_transpose<true><<<dim3(16, 24, 32), blk, 0, stream>>>(feat, disws, qws);
        else        fp_transpose<false><<<dim3(16, 24, 32), blk, 0, stream>>>(Xws, disws, qws);

        // X' = dis[m] * (adj^T @ (dis[n]*X))  (batched)
        gemm_nt<2, false><<<dim3(4, 6, 32), blk, 0, stream>>>(
            adjT, qws, nullptr, Xws,
            NODES, NODES, NODES, DIM, (long)NODES * NODES, (long)DIM * NODES, (long)NODES * DIM,
            nullptr, nullptr, nullptr, nullptr, nullptr, nullptr, nullptr, disws, 0);

        pool_kernel<false><<<dim3(4096), blk, 0, stream>>>(Xws, projw, projb, ob + RET_OFF, out_acc,
                                                           ob + OUT_OFF, l + 1, (l == LAYERS - 1) ? 2 : 1);
    }

    finalize_kernel<<<dim3(1), dim3(128), 0, stream>>>(p_sum, c_acc, g_acc, l0_acc, ob);
}

// Round 3
// 982.948 us; speedup vs baseline: 1.0913x; 1.0913x over previous
//
#include <hip/hip_runtime.h>

typedef short s16x8 __attribute__((ext_vector_type(8)));
typedef float f32x4 __attribute__((ext_vector_type(4)));

constexpr int BATCH = 32, NODES = 512, DIM = 768, LAYERS = 4;
constexpr float QK_SCALE = 0.03608439182435161f;  // 1/sqrt(768)

constexpr size_t OUT_OFF  = 0;
constexpr size_t RET_OFF  = (size_t)BATCH * NODES * DIM;                       // 12582912
constexpr size_t ADJS_OFF = RET_OFF + (size_t)BATCH * NODES * (LAYERS + 1);    // 12664832
constexpr size_t L0_OFF   = ADJS_OFF + (size_t)BATCH * NODES * NODES * LAYERS; // 46219264
constexpr size_t C_OFF    = L0_OFF + 1;
constexpr size_t G_OFF    = C_OFF + BATCH * LAYERS;

#define DEVI static __device__ __forceinline__

DEVI float bf2f(unsigned short u) {
    union { unsigned int i; float f; } v; v.i = ((unsigned int)u) << 16; return v.f;
}
DEVI unsigned short f2bf(float f) {
    union { float f; unsigned int i; } v; v.f = f;
    return (unsigned short)((v.i + 0x7FFFu + ((v.i >> 16) & 1u)) >> 16);
}
DEVI ushort4 pk4(float4 v) {
    ushort4 o; o.x = f2bf(v.x); o.y = f2bf(v.y); o.z = f2bf(v.z); o.w = f2bf(v.w); return o;
}
DEVI float sigm(float x) { return 1.0f / (1.0f + __expf(-x)); }

// async global->LDS, 16B per lane; lds base must be wave-uniform (deposit = base + lane*16)
DEVI void gload16(const unsigned short* g, unsigned short* l) {
    __builtin_amdgcn_global_load_lds(
        (const __attribute__((address_space(1))) unsigned int*)g,
        (__attribute__((address_space(3))) unsigned int*)l, 16, 0, 0);
}

// ---------------------------------------------------------------------------
// NT GEMM: C[m,n] = sum_k A[m,k] * B[n,k]   (bf16 in, f32 acc, bf16 out)
// 128x128 tile, BK=32, unpadded LDS (global_load_lds-compatible), m97-style.
// MODE 0: proj (z in {0,1} selects Wq^T/Wk^T; C z-stride lands q then k)
// MODE 1: scores (adj = sigmoid(S*scale)*pm_n*pm_m; writes adjT bf16 [m][n];
//         accumulates deg/l0/c/g)
// MODE 2: aggregation (epilogue: *= dis[row], bf16 store)
// ---------------------------------------------------------------------------
template <int MODE>
__global__ __launch_bounds__(256) void gemm_nt(
    const unsigned short* __restrict__ A0, const unsigned short* __restrict__ Bq,
    const unsigned short* __restrict__ Bk, unsigned short* __restrict__ C0,
    int K, int lda, int ldb, int ldc,
    long sA, long sB, long sC,
    const float* __restrict__ pmask, float* __restrict__ deg,
    unsigned short* __restrict__ adjT,
    float* __restrict__ l0_acc, float* __restrict__ c_acc, float* __restrict__ g_acc,
    const float* __restrict__ dis, int layer)
{
    __shared__ __align__(16) unsigned short As[128 * 32];
    __shared__ __align__(16) unsigned short Bs[128 * 32];
    __shared__ float pmr[128];
    __shared__ float pmc[128];

    const int tid  = threadIdx.x;
    const int lane = tid & 63;
    const int wave = tid >> 6;
    const int wr = (wave >> 1) << 6;
    const int wc = (wave & 1) << 6;
    const int z = blockIdx.z;
    const int rows0 = blockIdx.x << 7;
    const int cols0 = blockIdx.y << 7;

    const unsigned short* A = A0 + (size_t)z * sA + (size_t)rows0 * lda;
    const unsigned short* Bsrc = ((MODE == 0 && z == 1) ? Bk : Bq) + (size_t)z * sB + (size_t)cols0 * ldb;

    f32x4 acc[4][4] = {};

    // staging map: thread t -> row = wave*16 + (lane>>2), colblock = lane&3 (8 elems)
    const int srow = wave * 16 + (lane >> 2);
    const int scb  = (lane & 3) << 3;
    const unsigned short* Ag = A + (size_t)srow * lda + scb;
    const unsigned short* Bg = Bsrc + (size_t)srow * ldb + scb;
    unsigned short* lA0 = &As[wave * 512];
    unsigned short* lA1 = &As[2048 + wave * 512];
    unsigned short* lB0 = &Bs[wave * 512];
    unsigned short* lB1 = &Bs[2048 + wave * 512];
    const size_t a64 = (size_t)64 * lda, b64 = (size_t)64 * ldb;

    const int mrow = lane & 15;
    const int kq   = (lane >> 4) << 3;

    for (int kt = 0; kt < K; kt += 32) {
        __syncthreads();
        gload16(Ag + kt, lA0);
        gload16(Ag + a64 + kt, lA1);
        gload16(Bg + kt, lB0);
        gload16(Bg + b64 + kt, lB1);
        __syncthreads();

        s16x8 af[4], bfr[4];
        #pragma unroll
        for (int i = 0; i < 4; ++i) {
            af[i]  = *(const s16x8*)(&As[(wr + i * 16 + mrow) * 32 + kq]);
            bfr[i] = *(const s16x8*)(&Bs[(wc + i * 16 + mrow) * 32 + kq]);
        }
        #pragma unroll
        for (int i = 0; i < 4; ++i)
            #pragma unroll
            for (int j = 0; j < 4; ++j)
                acc[i][j] = __builtin_amdgcn_mfma_f32_16x16x32_bf16(af[i], bfr[j], acc[i][j], 0, 0, 0);
    }

    const int colb = lane & 15, quad = lane >> 4;

    if constexpr (MODE != 1) {
        unsigned short* C = C0 + (size_t)z * sC;
        #pragma unroll
        for (int i = 0; i < 4; ++i) {
            const int rbase = rows0 + wr + i * 16 + (quad << 2);
            float dv[4];
            if constexpr (MODE == 2) {
                #pragma unroll
                for (int r = 0; r < 4; ++r) dv[r] = dis[(size_t)z * NODES + rbase + r];
            }
            #pragma unroll
            for (int j = 0; j < 4; ++j) {
                const int cc = cols0 + wc + j * 16 + colb;
                #pragma unroll
                for (int r = 0; r < 4; ++r) {
                    float v = acc[i][j][r];
                    if constexpr (MODE == 2) v *= dv[r];
                    C[(size_t)(rbase + r) * ldc + cc] = f2bf(v);
                }
            }
        }
    } else {
        __syncthreads();
        if (tid < 128) pmr[tid] = pmask[(size_t)z * NODES + rows0 + tid];
        else if (tid < 256) pmc[tid - 128] = pmask[(size_t)z * NODES + cols0 + (tid - 128)];
        __syncthreads();

        float tot = 0.f, gs = 0.f, cs = 0.f;
        #pragma unroll
        for (int i = 0; i < 4; ++i) {
            const int nloc = wr + i * 16 + (quad << 2);
            #pragma unroll
            for (int r = 0; r < 4; ++r) {
                const int n = rows0 + nloc + r;
                const float pmn = pmr[nloc + r];
                float dp = 0.f;
                #pragma unroll
                for (int j = 0; j < 4; ++j) {
                    const int mloc = wc + j * 16 + colb;
                    const int m = cols0 + mloc;
                    float a = pmn * pmc[mloc] * sigm(acc[i][j][r] * QK_SCALE);
                    acc[i][j][r] = a;
                    dp += a;
                    tot += a;
                    if (m < NODES - 1) {
                        if (n < NODES - 1) gs += a;
                        else cs += a;
                    }
                }
                dp += __shfl_xor(dp, 1, 16);
                dp += __shfl_xor(dp, 2, 16);
                dp += __shfl_xor(dp, 4, 16);
                dp += __shfl_xor(dp, 8, 16);
                if (colb == 0) atomicAdd(&deg[(size_t)z * NODES + n], dp);
            }
        }
        // adj^T (bf16, [b][m][n]) into this layer's slice (also feeds agg GEMM)
        #pragma unroll
        for (int i = 0; i < 4; ++i) {
            const int nb = rows0 + wr + i * 16 + (quad << 2);
            #pragma unroll
            for (int j = 0; j < 4; ++j) {
                const int m = cols0 + wc + j * 16 + colb;
                ushort4 pk;
                pk.x = f2bf(acc[i][j][0]); pk.y = f2bf(acc[i][j][1]);
                pk.z = f2bf(acc[i][j][2]); pk.w = f2bf(acc[i][j][3]);
                *(ushort4*)(adjT + ((size_t)z * NODES + m) * NODES + nb) = pk;
            }
        }
        #pragma unroll
        for (int o = 1; o < 64; o <<= 1) {
            tot += __shfl_xor(tot, o, 64);
            gs  += __shfl_xor(gs, o, 64);
            cs  += __shfl_xor(cs, o, 64);
        }
        if (lane == 0) {
            atomicAdd(l0_acc, tot);
            atomicAdd(&g_acc[z * LAYERS + layer], gs);
            atomicAdd(&c_acc[z * LAYERS + layer], cs);
        }
    }
}

// ---------------------------------------------------------------------------
// adjs[b][n][m][l] = f32(adjT[l][b][m][n])  — LDS-transposed, coalesced stores
// ---------------------------------------------------------------------------
__global__ __launch_bounds__(256) void interleave_adjs(
    const unsigned short* __restrict__ adjT, float* __restrict__ adjs)
{
    __shared__ unsigned short t[4][32][36];
    const int b = blockIdx.z, m0 = blockIdx.x << 5, n0 = blockIdx.y << 5;
    const int tr = threadIdx.x >> 3, tc = (threadIdx.x & 7) << 2;
    #pragma unroll
    for (int l = 0; l < LAYERS; ++l) {
        ushort4 v = *(const ushort4*)(adjT + (((size_t)l * BATCH + b) * NODES + m0 + tr) * NODES + n0 + tc);
        t[l][tr][tc] = v.x; t[l][tr][tc + 1] = v.y; t[l][tr][tc + 2] = v.z; t[l][tr][tc + 3] = v.w;
    }
    __syncthreads();
    float* dst = adjs + (((size_t)b * NODES + n0 + tr) * NODES + m0 + tc) * LAYERS;
    #pragma unroll
    for (int mm = 0; mm < 4; ++mm) {
        float4 f;
        f.x = bf2f(t[0][tc + mm][tr]); f.y = bf2f(t[1][tc + mm][tr]);
        f.z = bf2f(t[2][tc + mm][tr]); f.w = bf2f(t[3][tc + mm][tr]);
        *(float4*)(dst + mm * 4) = f;
    }
}

// ---------------------------------------------------------------------------
// W^T: Wt[l][n][k] = bf16(W[l][k][n])  (768x768 f32 -> bf16), z = which*4 + l
// ---------------------------------------------------------------------------
__global__ void transpose_w(const float* __restrict__ Wq, const float* __restrict__ Wk,
                            unsigned short* __restrict__ Wqt, unsigned short* __restrict__ Wkt)
{
    __shared__ unsigned short t[32][36];
    const int which = blockIdx.z >> 2, l = blockIdx.z & 3;
    const float* src = (which ? Wk : Wq) + (size_t)l * DIM * DIM;
    unsigned short* dst = (which ? Wkt : Wqt) + (size_t)l * DIM * DIM;
    const int r0 = blockIdx.x << 5, c0 = blockIdx.y << 5;
    const int tr = threadIdx.x >> 3, tc = (threadIdx.x & 7) << 2;
    float4 v = *(const float4*)(src + (size_t)(r0 + tr) * DIM + c0 + tc);
    t[tr][tc] = f2bf(v.x); t[tr][tc + 1] = f2bf(v.y);
    t[tr][tc + 2] = f2bf(v.z); t[tr][tc + 3] = f2bf(v.w);
    __syncthreads();
    ushort4 o;
    o.x = t[tc + 0][tr]; o.y = t[tc + 1][tr]; o.z = t[tc + 2][tr]; o.w = t[tc + 3][tr];
    *(ushort4*)(dst + (size_t)(c0 + tr) * DIM + r0 + tc) = o;
}

// ---------------------------------------------------------------------------
// fp_t[b][d][n] = bf16(dis[b][n] * X[b][n][d])   (X bf16)
// ---------------------------------------------------------------------------
__global__ void fp_transpose(const unsigned short* __restrict__ X, const float* __restrict__ dis,
                             unsigned short* __restrict__ fpt)
{
    __shared__ unsigned short t[32][36];
    const int b = blockIdx.z;
    const int n0 = blockIdx.x << 5, d0 = blockIdx.y << 5;
    const int tr = threadIdx.x >> 3, tc = (threadIdx.x & 7) << 2;
    const float dv = dis[(size_t)b * NODES + n0 + tr];
    ushort4 v = *(const ushort4*)(X + ((size_t)b * NODES + n0 + tr) * DIM + d0 + tc);
    t[tr][tc]     = f2bf(bf2f(v.x) * dv);
    t[tr][tc + 1] = f2bf(bf2f(v.y) * dv);
    t[tr][tc + 2] = f2bf(bf2f(v.z) * dv);
    t[tr][tc + 3] = f2bf(bf2f(v.w) * dv);
    __syncthreads();
    ushort4 o;
    o.x = t[tc + 0][tr]; o.y = t[tc + 1][tr]; o.z = t[tc + 2][tr]; o.w = t[tc + 3][tr];
    *(ushort4*)(fpt + ((size_t)b * DIM + d0 + tr) * NODES + n0 + tc) = o;
}

__global__ void f2bf_kernel(const float* __restrict__ x, unsigned short* __restrict__ y)
{
    const size_t i = ((size_t)blockIdx.x * 256 + threadIdx.x) << 2;
    float4 v = *(const float4*)(x + i);
    *(ushort4*)(y + i) = pk4(v);
}

__global__ void dis_kernel(const float* __restrict__ deg, float* __restrict__ dis)
{
    const int i = blockIdx.x * 256 + threadIdx.x;
    const float d = deg[i];
    dis[i] = d > 0.f ? rsqrtf(fmaxf(d, 1e-12f)) : 0.f;
}

__global__ void psum_kernel(const float* __restrict__ pm, float* __restrict__ ps)
{
    const int b = blockIdx.x, t = threadIdx.x;
    float s = pm[(size_t)b * NODES + t] + pm[(size_t)b * NODES + 256 + t];
    #pragma unroll
    for (int o = 1; o < 64; o <<= 1) s += __shfl_xor(s, o, 64);
    __shared__ float sh[4];
    if ((t & 63) == 0) sh[t >> 6] = s;
    __syncthreads();
    if (t == 0) ps[b] = sh[0] + sh[1] + sh[2] + sh[3];
}

// ---------------------------------------------------------------------------
// Attention-pool per pred: r = sigmoid(X.w + b); retain[:,:,lp] = r;
// mode 0: acc = r*X    mode 1: acc += r*X    mode 2: out = acc + r*X
// One wave per (b,n) row. X f32 (pred 0) or bf16 (later preds).
// ---------------------------------------------------------------------------
template <bool XF32>
__global__ __launch_bounds__(256) void pool_kernel(
    const void* __restrict__ Xv, const float* __restrict__ pw,
    const float* __restrict__ pb, float* __restrict__ ret,
    float* __restrict__ acc, float* __restrict__ outb, int lp, int mode)
{
    const int row = (blockIdx.x << 2) + (threadIdx.x >> 6);
    const int lane = threadIdx.x & 63;
    float xs[12];
    float dot = 0.f;
    #pragma unroll
    for (int c = 0; c < 3; ++c) {
        const int idx = c * 256 + (lane << 2);
        float4 wv = *(const float4*)(pw + idx);
        float a0, a1, a2, a3;
        if constexpr (XF32) {
            float4 xv = *(const float4*)((const float*)Xv + (size_t)row * DIM + idx);
            a0 = xv.x; a1 = xv.y; a2 = xv.z; a3 = xv.w;
        } else {
            ushort4 xv = *(const ushort4*)((const unsigned short*)Xv + (size_t)row * DIM + idx);
            a0 = bf2f(xv.x); a1 = bf2f(xv.y); a2 = bf2f(xv.z); a3 = bf2f(xv.w);
        }
        xs[c * 4 + 0] = a0; xs[c * 4 + 1] = a1; xs[c * 4 + 2] = a2; xs[c * 4 + 3] = a3;
        dot += a0 * wv.x + a1 * wv.y + a2 * wv.z + a3 * wv.w;
    }
    #pragma unroll
    for (int o = 1; o < 64; o <<= 1) dot += __shfl_xor(dot, o, 64);
    const float r = sigm(dot + pb[0]);
    if (lane == 0) ret[(size_t)row * (LAYERS + 1) + lp] = r;
    float* ar = acc + (size_t)row * DIM;
    float* orow = outb + (size_t)row * DIM;
    #pragma unroll
    for (int c = 0; c < 3; ++c) {
        const int idx = c * 256 + (lane << 2);
        float a0 = r * xs[c * 4 + 0], a1 = r * xs[c * 4 + 1];
        float a2 = r * xs[c * 4 + 2], a3 = r * xs[c * 4 + 3];
        if (mode != 0) {
            float4 p = *(const float4*)(ar + idx);
            a0 += p.x; a1 += p.y; a2 += p.z; a3 += p.w;
        }
        float4 p; p.x = a0; p.y = a1; p.z = a2; p.w = a3;
        if (mode == 2) *(float4*)(orow + idx) = p;
        else           *(float4*)(ar + idx) = p;
    }
}

__global__ void finalize_kernel(const float* __restrict__ ps, const float* __restrict__ c_acc,
                                const float* __restrict__ g_acc, const float* __restrict__ l0,
                                float* __restrict__ ob)
{
    const int t = threadIdx.x;
    if (t < BATCH * LAYERS) {
        const int b = t >> 2;
        const float p = ps[b];
        ob[C_OFF + t] = c_acc[t] / p;
        ob[G_OFF + t] = g_acc[t] / (p * p);
    }
    if (t == 0) {
        float fs = 1e-8f;
        for (int b = 0; b < BATCH; ++b) fs += ps[b] * ps[b];
        ob[L0_OFF] = l0[0] / (fs * (float)LAYERS);
    }
}

// ---------------------------------------------------------------------------
extern "C" void kernel_launch(void* const* d_in, const int* in_sizes, int n_in,
                              void* d_out, int out_size, void* d_ws, size_t ws_size,
                              hipStream_t stream)
{
    (void)in_sizes; (void)n_in; (void)out_size; (void)ws_size;
    const float* pmask = (const float*)d_in[0];
    const float* feat  = (const float*)d_in[1];
    const float* Wq    = (const float*)d_in[2];
    const float* Wk    = (const float*)d_in[3];
    const float* projw = (const float*)d_in[4];
    const float* projb = (const float*)d_in[5];
    float* ob = (float*)d_out;

    char* w = (char*)d_ws;
    unsigned short* Xws   = (unsigned short*)(w + 0);          //  25165824 B bf16 [B,N,D]
    unsigned short* qws   = (unsigned short*)(w + 25165824);   //  25165824 B bf16 q / fp_t
    unsigned short* kws   = (unsigned short*)(w + 50331648);   //  25165824 B bf16 k
    unsigned short* featb = (unsigned short*)(w + 75497472);   //  25165824 B bf16 feat
    unsigned short* adjT  = (unsigned short*)(w + 100663296);  //  67108864 B bf16 [L,B,m,n]
    unsigned short* Wqt   = (unsigned short*)(w + 167772160);  //   4718592 B bf16
    unsigned short* Wkt   = (unsigned short*)(w + 172490752);  //   4718592 B bf16
    float* out_acc = (float*)(w + 177209344);                  //  50331648 B f32 [B,N,D]
    float* deg_all = (float*)(w + 227540992);                  //    262144 B f32 [L,B,N]
    float* c_acc   = (float*)(w + 227803136);                  //       512 B
    float* g_acc   = (float*)(w + 227803648);                  //       512 B
    float* l0_acc  = (float*)(w + 227804160);                  //       256 B
    float* disws   = (float*)(w + 227804416);                  //     65536 B f32 [B,N]
    float* p_sum   = (float*)(w + 227869952);                  //       256 B

    dim3 blk(256);
    hipMemsetAsync(w + 227540992, 0, 263680, stream);  // deg_all + c_acc + g_acc + l0_acc

    f2bf_kernel<<<dim3(12288), blk, 0, stream>>>(feat, featb);
    transpose_w<<<dim3(24, 24, 8), blk, 0, stream>>>(Wq, Wk, Wqt, Wkt);
    psum_kernel<<<dim3(32), blk, 0, stream>>>(pmask, p_sum);
    pool_kernel<true><<<dim3(4096), blk, 0, stream>>>(feat, projw, projb, ob + RET_OFF, out_acc, ob + OUT_OFF, 0, 0);

    for (int l = 0; l < LAYERS; ++l) {
        float* deg_l = deg_all + (size_t)l * BATCH * NODES;
        unsigned short* adjT_l = adjT + (size_t)l * BATCH * NODES * NODES;
        const unsigned short* Xsrc = (l == 0) ? featb : Xws;

        // q = X @ Wq[l], k = X @ Wk[l]  (z selects q/k; C z-stride: qws then kws)
        gemm_nt<0><<<dim3(128, 6, 2), blk, 0, stream>>>(
            Xsrc, Wqt + (size_t)l * DIM * DIM, Wkt + (size_t)l * DIM * DIM, qws,
            DIM, DIM, DIM, DIM, 0L, 0L, (long)BATCH * NODES * DIM,
            nullptr, nullptr, nullptr, nullptr, nullptr, nullptr, nullptr, 0);

        // S = q @ k^T (batched) + sigmoid/mask/stats epilogue, writes adjT_l
        gemm_nt<1><<<dim3(4, 4, 32), blk, 0, stream>>>(
            qws, kws, nullptr, nullptr,
            DIM, DIM, DIM, 0, (long)NODES * DIM, (long)NODES * DIM, 0L,
            pmask, deg_l, adjT_l, l0_acc, c_acc, g_acc, nullptr, l);

        dis_kernel<<<dim3(64), blk, 0, stream>>>(deg_l, disws);
        fp_transpose<<<dim3(16, 24, 32), blk, 0, stream>>>(Xsrc, disws, qws);

        // X' = dis[m] * (adjT_l @ (dis[n]*X))  (batched)
        gemm_nt<2><<<dim3(4, 6, 32), blk, 0, stream>>>(
            adjT_l, qws, nullptr, Xws,
            NODES, NODES, NODES, DIM, (long)NODES * NODES, (long)DIM * NODES, (long)NODES * DIM,
            nullptr, nullptr, nullptr, nullptr, nullptr, nullptr, disws, 0);

        pool_kernel<false><<<dim3(4096), blk, 0, stream>>>(Xws, projw, projb, ob + RET_OFF, out_acc,
                                                           ob + OUT_OFF, l + 1, (l == LAYERS - 1) ? 2 : 1);
    }

    interleave_adjs<<<dim3(16, 16, 32), blk, 0, stream>>>(adjT, ob + ADJS_OFF);
    finalize_kernel<<<dim3(1), dim3(128), 0, stream>>>(p_sum, c_acc, g_acc, l0_acc, ob);
}

// Round 4
// 915.039 us; speedup vs baseline: 1.1723x; 1.0742x over previous
//
#include <hip/hip_runtime.h>

typedef short s16x8 __attribute__((ext_vector_type(8)));
typedef float f32x4 __attribute__((ext_vector_type(4)));

constexpr int BATCH = 32, NODES = 512, DIM = 768, LAYERS = 4;
constexpr float QK_SCALE = 0.03608439182435161f;  // 1/sqrt(768)

constexpr size_t OUT_OFF  = 0;
constexpr size_t RET_OFF  = (size_t)BATCH * NODES * DIM;                       // 12582912
constexpr size_t ADJS_OFF = RET_OFF + (size_t)BATCH * NODES * (LAYERS + 1);    // 12664832
constexpr size_t L0_OFF   = ADJS_OFF + (size_t)BATCH * NODES * NODES * LAYERS; // 46219264
constexpr size_t C_OFF    = L0_OFF + 1;
constexpr size_t G_OFF    = C_OFF + BATCH * LAYERS;

#define DEVI static __device__ __forceinline__

DEVI float bf2f(unsigned short u) {
    union { unsigned int i; float f; } v; v.i = ((unsigned int)u) << 16; return v.f;
}
DEVI unsigned short f2bf(float f) {
    union { float f; unsigned int i; } v; v.f = f;
    return (unsigned short)((v.i + 0x7FFFu + ((v.i >> 16) & 1u)) >> 16);
}
DEVI ushort4 pk4(float4 v) {
    ushort4 o; o.x = f2bf(v.x); o.y = f2bf(v.y); o.z = f2bf(v.z); o.w = f2bf(v.w); return o;
}
DEVI float sigm(float x) { return 1.0f / (1.0f + __expf(-x)); }
DEVI float deg2dis(float d) { return d > 0.f ? rsqrtf(fmaxf(d, 1e-12f)) : 0.f; }

// async global->LDS, 16B per lane; lds base must be wave-uniform (deposit = base + lane*16)
DEVI void gload16(const unsigned short* g, unsigned short* l) {
    __builtin_amdgcn_global_load_lds(
        (const __attribute__((address_space(1))) unsigned int*)g,
        (__attribute__((address_space(3))) unsigned int*)l, 16, 0, 0);
}

// ---------------------------------------------------------------------------
// NT GEMM: C[m,n] = sum_k A[m,k] * B[n,k]   (bf16 in, f32 acc, bf16 out)
// 128x128 tile, BK=32, unpadded LDS (global_load_lds staging), m97-style.
// MODE 0: proj (z in {0,1} selects Wq^T/Wk^T; C z-stride lands q then k)
// MODE 1: scores (adj = sigmoid(S*scale)*pm_n*pm_m; writes adjT bf16 [m][n];
//         accumulates deg/l0/c/g)
// MODE 2: aggregation (epilogue: *= deg2dis(deg[row]), bf16 store)
// ---------------------------------------------------------------------------
template <int MODE>
__global__ __launch_bounds__(256) void gemm_nt(
    const unsigned short* __restrict__ A0, const unsigned short* __restrict__ Bq,
    const unsigned short* __restrict__ Bk, unsigned short* __restrict__ C0,
    int K, int lda, int ldb, int ldc,
    long sA, long sB, long sC,
    const float* __restrict__ pmask, float* __restrict__ deg,
    unsigned short* __restrict__ adjT,
    float* __restrict__ l0_acc, float* __restrict__ c_acc, float* __restrict__ g_acc,
    int layer)
{
    __shared__ __align__(16) unsigned short As[128 * 32];
    __shared__ __align__(16) unsigned short Bs[128 * 32];
    __shared__ float pmr[128];
    __shared__ float pmc[128];

    const int tid  = threadIdx.x;
    const int lane = tid & 63;
    const int wave = tid >> 6;
    const int wr = (wave >> 1) << 6;
    const int wc = (wave & 1) << 6;
    const int z = blockIdx.z;
    const int rows0 = blockIdx.x << 7;
    const int cols0 = blockIdx.y << 7;

    const unsigned short* A = A0 + (size_t)z * sA + (size_t)rows0 * lda;
    const unsigned short* Bsrc = ((MODE == 0 && z == 1) ? Bk : Bq) + (size_t)z * sB + (size_t)cols0 * ldb;

    f32x4 acc[4][4] = {};

    // staging map: thread t -> row = wave*16 + (lane>>2), colblock = lane&3 (8 elems)
    const int srow = wave * 16 + (lane >> 2);
    const int scb  = (lane & 3) << 3;
    const unsigned short* Ag = A + (size_t)srow * lda + scb;
    const unsigned short* Bg = Bsrc + (size_t)srow * ldb + scb;
    unsigned short* lA0 = &As[wave * 512];
    unsigned short* lA1 = &As[2048 + wave * 512];
    unsigned short* lB0 = &Bs[wave * 512];
    unsigned short* lB1 = &Bs[2048 + wave * 512];
    const size_t a64 = (size_t)64 * lda, b64 = (size_t)64 * ldb;

    const int mrow = lane & 15;
    const int kq   = (lane >> 4) << 3;

    for (int kt = 0; kt < K; kt += 32) {
        __syncthreads();
        gload16(Ag + kt, lA0);
        gload16(Ag + a64 + kt, lA1);
        gload16(Bg + kt, lB0);
        gload16(Bg + b64 + kt, lB1);
        __syncthreads();

        s16x8 af[4], bfr[4];
        #pragma unroll
        for (int i = 0; i < 4; ++i) {
            af[i]  = *(const s16x8*)(&As[(wr + i * 16 + mrow) * 32 + kq]);
            bfr[i] = *(const s16x8*)(&Bs[(wc + i * 16 + mrow) * 32 + kq]);
        }
        #pragma unroll
        for (int i = 0; i < 4; ++i)
            #pragma unroll
            for (int j = 0; j < 4; ++j)
                acc[i][j] = __builtin_amdgcn_mfma_f32_16x16x32_bf16(af[i], bfr[j], acc[i][j], 0, 0, 0);
    }

    const int colb = lane & 15, quad = lane >> 4;

    if constexpr (MODE != 1) {
        unsigned short* C = C0 + (size_t)z * sC;
        #pragma unroll
        for (int i = 0; i < 4; ++i) {
            const int rbase = rows0 + wr + i * 16 + (quad << 2);
            float dv[4];
            if constexpr (MODE == 2) {
                #pragma unroll
                for (int r = 0; r < 4; ++r) dv[r] = deg2dis(deg[(size_t)z * NODES + rbase + r]);
            }
            #pragma unroll
            for (int j = 0; j < 4; ++j) {
                const int cc = cols0 + wc + j * 16 + colb;
                #pragma unroll
                for (int r = 0; r < 4; ++r) {
                    float v = acc[i][j][r];
                    if constexpr (MODE == 2) v *= dv[r];
                    C[(size_t)(rbase + r) * ldc + cc] = f2bf(v);
                }
            }
        }
    } else {
        __syncthreads();
        if (tid < 128) pmr[tid] = pmask[(size_t)z * NODES + rows0 + tid];
        else if (tid < 256) pmc[tid - 128] = pmask[(size_t)z * NODES + cols0 + (tid - 128)];
        __syncthreads();

        float tot = 0.f, gs = 0.f, cs = 0.f;
        #pragma unroll
        for (int i = 0; i < 4; ++i) {
            const int nloc = wr + i * 16 + (quad << 2);
            #pragma unroll
            for (int r = 0; r < 4; ++r) {
                const int n = rows0 + nloc + r;
                const float pmn = pmr[nloc + r];
                float dp = 0.f;
                #pragma unroll
                for (int j = 0; j < 4; ++j) {
                    const int mloc = wc + j * 16 + colb;
                    const int m = cols0 + mloc;
                    float a = pmn * pmc[mloc] * sigm(acc[i][j][r] * QK_SCALE);
                    acc[i][j][r] = a;
                    dp += a;
                    tot += a;
                    if (m < NODES - 1) {
                        if (n < NODES - 1) gs += a;
                        else cs += a;
                    }
                }
                dp += __shfl_xor(dp, 1, 16);
                dp += __shfl_xor(dp, 2, 16);
                dp += __shfl_xor(dp, 4, 16);
                dp += __shfl_xor(dp, 8, 16);
                if (colb == 0) atomicAdd(&deg[(size_t)z * NODES + n], dp);
            }
        }
        // adj^T (bf16, [b][m][n]) into this layer's slice (also feeds agg GEMM)
        #pragma unroll
        for (int i = 0; i < 4; ++i) {
            const int nb = rows0 + wr + i * 16 + (quad << 2);
            #pragma unroll
            for (int j = 0; j < 4; ++j) {
                const int m = cols0 + wc + j * 16 + colb;
                ushort4 pk;
                pk.x = f2bf(acc[i][j][0]); pk.y = f2bf(acc[i][j][1]);
                pk.z = f2bf(acc[i][j][2]); pk.w = f2bf(acc[i][j][3]);
                *(ushort4*)(adjT + ((size_t)z * NODES + m) * NODES + nb) = pk;
            }
        }
        #pragma unroll
        for (int o = 1; o < 64; o <<= 1) {
            tot += __shfl_xor(tot, o, 64);
            gs  += __shfl_xor(gs, o, 64);
            cs  += __shfl_xor(cs, o, 64);
        }
        if (lane == 0) {
            atomicAdd(l0_acc, tot);
            atomicAdd(&g_acc[z * LAYERS + layer], gs);
            atomicAdd(&c_acc[z * LAYERS + layer], cs);
        }
    }
}

// ---------------------------------------------------------------------------
// adjs[b][n][m][l] = f32(adjT[l][b][m][n])  — LDS-transposed, coalesced stores
// ---------------------------------------------------------------------------
__global__ __launch_bounds__(256) void interleave_adjs(
    const unsigned short* __restrict__ adjT, float* __restrict__ adjs)
{
    __shared__ unsigned short t[4][32][36];
    const int b = blockIdx.z, m0 = blockIdx.x << 5, n0 = blockIdx.y << 5;
    const int tr = threadIdx.x >> 3, tc = (threadIdx.x & 7) << 2;
    #pragma unroll
    for (int l = 0; l < LAYERS; ++l) {
        ushort4 v = *(const ushort4*)(adjT + (((size_t)l * BATCH + b) * NODES + m0 + tr) * NODES + n0 + tc);
        t[l][tr][tc] = v.x; t[l][tr][tc + 1] = v.y; t[l][tr][tc + 2] = v.z; t[l][tr][tc + 3] = v.w;
    }
    __syncthreads();
    float* dst = adjs + (((size_t)b * NODES + n0 + tr) * NODES + m0 + tc) * LAYERS;
    #pragma unroll
    for (int mm = 0; mm < 4; ++mm) {
        float4 f;
        f.x = bf2f(t[0][tc + mm][tr]); f.y = bf2f(t[1][tc + mm][tr]);
        f.z = bf2f(t[2][tc + mm][tr]); f.w = bf2f(t[3][tc + mm][tr]);
        *(float4*)(dst + mm * 4) = f;
    }
}

// ---------------------------------------------------------------------------
// W^T: Wt[l][n][k] = bf16(W[l][k][n])  (768x768 f32 -> bf16), z = which*4 + l
// ---------------------------------------------------------------------------
__global__ void transpose_w(const float* __restrict__ Wq, const float* __restrict__ Wk,
                            unsigned short* __restrict__ Wqt, unsigned short* __restrict__ Wkt)
{
    __shared__ unsigned short t[32][36];
    const int which = blockIdx.z >> 2, l = blockIdx.z & 3;
    const float* src = (which ? Wk : Wq) + (size_t)l * DIM * DIM;
    unsigned short* dst = (which ? Wkt : Wqt) + (size_t)l * DIM * DIM;
    const int r0 = blockIdx.x << 5, c0 = blockIdx.y << 5;
    const int tr = threadIdx.x >> 3, tc = (threadIdx.x & 7) << 2;
    float4 v = *(const float4*)(src + (size_t)(r0 + tr) * DIM + c0 + tc);
    t[tr][tc] = f2bf(v.x); t[tr][tc + 1] = f2bf(v.y);
    t[tr][tc + 2] = f2bf(v.z); t[tr][tc + 3] = f2bf(v.w);
    __syncthreads();
    ushort4 o;
    o.x = t[tc + 0][tr]; o.y = t[tc + 1][tr]; o.z = t[tc + 2][tr]; o.w = t[tc + 3][tr];
    *(ushort4*)(dst + (size_t)(c0 + tr) * DIM + r0 + tc) = o;
}

// ---------------------------------------------------------------------------
// fp_t[b][d][n] = bf16(deg2dis(deg[b][n]) * X[b][n][d])   (X bf16)
// ---------------------------------------------------------------------------
__global__ void fp_transpose(const unsigned short* __restrict__ X, const float* __restrict__ deg,
                             unsigned short* __restrict__ fpt)
{
    __shared__ unsigned short t[32][36];
    const int b = blockIdx.z;
    const int n0 = blockIdx.x << 5, d0 = blockIdx.y << 5;
    const int tr = threadIdx.x >> 3, tc = (threadIdx.x & 7) << 2;
    const float dv = deg2dis(deg[(size_t)b * NODES + n0 + tr]);
    ushort4 v = *(const ushort4*)(X + ((size_t)b * NODES + n0 + tr) * DIM + d0 + tc);
    t[tr][tc]     = f2bf(bf2f(v.x) * dv);
    t[tr][tc + 1] = f2bf(bf2f(v.y) * dv);
    t[tr][tc + 2] = f2bf(bf2f(v.z) * dv);
    t[tr][tc + 3] = f2bf(bf2f(v.w) * dv);
    __syncthreads();
    ushort4 o;
    o.x = t[tc + 0][tr]; o.y = t[tc + 1][tr]; o.z = t[tc + 2][tr]; o.w = t[tc + 3][tr];
    *(ushort4*)(fpt + ((size_t)b * DIM + d0 + tr) * NODES + n0 + tc) = o;
}

__global__ void f2bf_kernel(const float* __restrict__ x, unsigned short* __restrict__ y)
{
    const size_t i = ((size_t)blockIdx.x * 256 + threadIdx.x) << 2;
    float4 v = *(const float4*)(x + i);
    *(ushort4*)(y + i) = pk4(v);
}

__global__ void psum_kernel(const float* __restrict__ pm, float* __restrict__ ps)
{
    const int b = blockIdx.x, t = threadIdx.x;
    float s = pm[(size_t)b * NODES + t] + pm[(size_t)b * NODES + 256 + t];
    #pragma unroll
    for (int o = 1; o < 64; o <<= 1) s += __shfl_xor(s, o, 64);
    __shared__ float sh[4];
    if ((t & 63) == 0) sh[t >> 6] = s;
    __syncthreads();
    if (t == 0) ps[b] = sh[0] + sh[1] + sh[2] + sh[3];
}

// ---------------------------------------------------------------------------
// Final fused output: all 5 preds in one pass. One wave per (b,n) row.
//   dot_l = X_l . w ; r_l = sigmoid(dot_l + b); retain[row][l] = r_l
//   out[row][:] = sum_l r_l * X_l[row][:]
// Also (block 0) finalizes c/g sparsity and l0 scalar.
// ---------------------------------------------------------------------------
__global__ __launch_bounds__(256) void final_out(
    const float* __restrict__ X0f, const unsigned short* __restrict__ X1,
    const unsigned short* __restrict__ X2, const unsigned short* __restrict__ X3,
    const unsigned short* __restrict__ X4,
    const float* __restrict__ pw, const float* __restrict__ pb,
    const float* __restrict__ ps, const float* __restrict__ c_acc,
    const float* __restrict__ g_acc, const float* __restrict__ l0,
    float* __restrict__ ob)
{
    if (blockIdx.x == 0) {
        const int t = threadIdx.x;
        if (t < BATCH * LAYERS) {
            const int b = t >> 2;
            const float p = ps[b];
            ob[C_OFF + t] = c_acc[t] / p;
            ob[G_OFF + t] = g_acc[t] / (p * p);
        }
        if (t == 0) {
            float fs = 1e-8f;
            for (int b = 0; b < BATCH; ++b) fs += ps[b] * ps[b];
            ob[L0_OFF] = l0[0] / (fs * (float)LAYERS);
        }
    }

    const int row = (blockIdx.x << 2) + (threadIdx.x >> 6);
    const int lane = threadIdx.x & 63;
    const unsigned short* Xb[4] = { X1 + (size_t)row * DIM, X2 + (size_t)row * DIM,
                                    X3 + (size_t)row * DIM, X4 + (size_t)row * DIM };
    float xs[5][12];
    float dot[5] = {};
    #pragma unroll
    for (int c = 0; c < 3; ++c) {
        const int idx = c * 256 + (lane << 2);
        float4 wv = *(const float4*)(pw + idx);
        float4 x0 = *(const float4*)(X0f + (size_t)row * DIM + idx);
        xs[0][c * 4 + 0] = x0.x; xs[0][c * 4 + 1] = x0.y;
        xs[0][c * 4 + 2] = x0.z; xs[0][c * 4 + 3] = x0.w;
        dot[0] += x0.x * wv.x + x0.y * wv.y + x0.z * wv.z + x0.w * wv.w;
        #pragma unroll
        for (int l = 0; l < 4; ++l) {
            ushort4 xv = *(const ushort4*)(Xb[l] + idx);
            float a0 = bf2f(xv.x), a1 = bf2f(xv.y), a2 = bf2f(xv.z), a3 = bf2f(xv.w);
            xs[l + 1][c * 4 + 0] = a0; xs[l + 1][c * 4 + 1] = a1;
            xs[l + 1][c * 4 + 2] = a2; xs[l + 1][c * 4 + 3] = a3;
            dot[l + 1] += a0 * wv.x + a1 * wv.y + a2 * wv.z + a3 * wv.w;
        }
    }
    #pragma unroll
    for (int l = 0; l < 5; ++l)
        #pragma unroll
        for (int o = 1; o < 64; o <<= 1) dot[l] += __shfl_xor(dot[l], o, 64);
    const float pbv = pb[0];
    float r[5];
    #pragma unroll
    for (int l = 0; l < 5; ++l) r[l] = sigm(dot[l] + pbv);
    if (lane == 0) {
        float* rr = ob + RET_OFF + (size_t)row * (LAYERS + 1);
        rr[0] = r[0]; rr[1] = r[1]; rr[2] = r[2]; rr[3] = r[3]; rr[4] = r[4];
    }
    float* orow = ob + OUT_OFF + (size_t)row * DIM;
    #pragma unroll
    for (int c = 0; c < 3; ++c) {
        float4 p;
        p.x = r[0] * xs[0][c * 4 + 0]; p.y = r[0] * xs[0][c * 4 + 1];
        p.z = r[0] * xs[0][c * 4 + 2]; p.w = r[0] * xs[0][c * 4 + 3];
        #pragma unroll
        for (int l = 1; l < 5; ++l) {
            p.x += r[l] * xs[l][c * 4 + 0]; p.y += r[l] * xs[l][c * 4 + 1];
            p.z += r[l] * xs[l][c * 4 + 2]; p.w += r[l] * xs[l][c * 4 + 3];
        }
        *(float4*)(orow + c * 256 + (lane << 2)) = p;
    }
}

// ---------------------------------------------------------------------------
extern "C" void kernel_launch(void* const* d_in, const int* in_sizes, int n_in,
                              void* d_out, int out_size, void* d_ws, size_t ws_size,
                              hipStream_t stream)
{
    (void)in_sizes; (void)n_in; (void)out_size; (void)ws_size;
    const float* pmask = (const float*)d_in[0];
    const float* feat  = (const float*)d_in[1];
    const float* Wq    = (const float*)d_in[2];
    const float* Wk    = (const float*)d_in[3];
    const float* projw = (const float*)d_in[4];
    const float* projb = (const float*)d_in[5];
    float* ob = (float*)d_out;

    char* w = (char*)d_ws;
    unsigned short* Xb[4];                                     // bf16 [B,N,D] per layer
    Xb[0] = (unsigned short*)(w + 0);
    Xb[1] = (unsigned short*)(w + 25165824);
    Xb[2] = (unsigned short*)(w + 50331648);
    Xb[3] = (unsigned short*)(w + 75497472);
    unsigned short* qws   = (unsigned short*)(w + 100663296);  //  25165824 B bf16 q / fp_t
    unsigned short* kws   = (unsigned short*)(w + 125829120);  //  25165824 B bf16 k
    unsigned short* featb = (unsigned short*)(w + 150994944);  //  25165824 B bf16 feat
    unsigned short* adjT  = (unsigned short*)(w + 176160768);  //  67108864 B bf16 [L,B,m,n]
    unsigned short* Wqt   = (unsigned short*)(w + 243269632);  //   4718592 B bf16
    unsigned short* Wkt   = (unsigned short*)(w + 247988224);  //   4718592 B bf16
    float* deg_all = (float*)(w + 252706816);                  //    262144 B f32 [L,B,N]
    float* c_acc   = (float*)(w + 252968960);                  //       512 B
    float* g_acc   = (float*)(w + 252969472);                  //       512 B
    float* l0_acc  = (float*)(w + 252969984);                  //       256 B
    float* p_sum   = (float*)(w + 252970240);                  //       256 B

    dim3 blk(256);
    hipMemsetAsync(w + 252706816, 0, 263680, stream);  // deg_all + c_acc + g_acc + l0_acc

    f2bf_kernel<<<dim3(12288), blk, 0, stream>>>(feat, featb);
    transpose_w<<<dim3(24, 24, 8), blk, 0, stream>>>(Wq, Wk, Wqt, Wkt);
    psum_kernel<<<dim3(32), blk, 0, stream>>>(pmask, p_sum);

    for (int l = 0; l < LAYERS; ++l) {
        float* deg_l = deg_all + (size_t)l * BATCH * NODES;
        unsigned short* adjT_l = adjT + (size_t)l * BATCH * NODES * NODES;
        const unsigned short* Xsrc = (l == 0) ? featb : Xb[l - 1];

        // q = X @ Wq[l], k = X @ Wk[l]  (z selects q/k; C z-stride: qws then kws)
        gemm_nt<0><<<dim3(128, 6, 2), blk, 0, stream>>>(
            Xsrc, Wqt + (size_t)l * DIM * DIM, Wkt + (size_t)l * DIM * DIM, qws,
            DIM, DIM, DIM, DIM, 0L, 0L, (long)BATCH * NODES * DIM,
            nullptr, nullptr, nullptr, nullptr, nullptr, nullptr, 0);

        // S = q @ k^T (batched) + sigmoid/mask/stats epilogue, writes adjT_l
        gemm_nt<1><<<dim3(4, 4, 32), blk, 0, stream>>>(
            qws, kws, nullptr, nullptr,
            DIM, DIM, DIM, 0, (long)NODES * DIM, (long)NODES * DIM, 0L,
            pmask, deg_l, adjT_l, l0_acc, c_acc, g_acc, l);

        fp_transpose<<<dim3(16, 24, 32), blk, 0, stream>>>(Xsrc, deg_l, qws);

        // X' = dis[m] * (adjT_l @ (dis[n]*X))  (batched)
        gemm_nt<2><<<dim3(4, 6, 32), blk, 0, stream>>>(
            adjT_l, qws, nullptr, Xb[l],
            NODES, NODES, NODES, DIM, (long)NODES * NODES, (long)DIM * NODES, (long)NODES * DIM,
            nullptr, deg_l, nullptr, nullptr, nullptr, nullptr, 0);
    }

    interleave_adjs<<<dim3(16, 16, 32), blk, 0, stream>>>(adjT, ob + ADJS_OFF);
    final_out<<<dim3(4096), blk, 0, stream>>>(feat, Xb[0], Xb[1], Xb[2], Xb[3],
                                              projw, projb, p_sum, c_acc, g_acc, l0_acc, ob);
}

// Round 5
// 838.685 us; speedup vs baseline: 1.2791x; 1.0910x over previous
//
#include <hip/hip_runtime.h>

typedef short s16x8 __attribute__((ext_vector_type(8)));
typedef float f32x4 __attribute__((ext_vector_type(4)));

constexpr int BATCH = 32, NODES = 512, DIM = 768, LAYERS = 4;
constexpr float QK_SCALE = 0.03608439182435161f;  // 1/sqrt(768)

constexpr size_t OUT_OFF  = 0;
constexpr size_t RET_OFF  = (size_t)BATCH * NODES * DIM;                       // 12582912
constexpr size_t ADJS_OFF = RET_OFF + (size_t)BATCH * NODES * (LAYERS + 1);    // 12664832
constexpr size_t L0_OFF   = ADJS_OFF + (size_t)BATCH * NODES * NODES * LAYERS; // 46219264
constexpr size_t C_OFF    = L0_OFF + 1;
constexpr size_t G_OFF    = C_OFF + BATCH * LAYERS;

#define DEVI static __device__ __forceinline__

DEVI float bf2f(unsigned short u) {
    union { unsigned int i; float f; } v; v.i = ((unsigned int)u) << 16; return v.f;
}
DEVI unsigned short f2bf(float f) {
    union { float f; unsigned int i; } v; v.f = f;
    return (unsigned short)((v.i + 0x7FFFu + ((v.i >> 16) & 1u)) >> 16);
}
DEVI ushort4 pk4(float4 v) {
    ushort4 o; o.x = f2bf(v.x); o.y = f2bf(v.y); o.z = f2bf(v.z); o.w = f2bf(v.w); return o;
}
DEVI float sigm(float x) { return 1.0f / (1.0f + __expf(-x)); }
DEVI float deg2dis(float d) { return d > 0.f ? rsqrtf(fmaxf(d, 1e-12f)) : 0.f; }

// async global->LDS, 16B per lane; lds base must be wave-uniform (deposit = base + lane*16)
DEVI void gload16(const unsigned short* g, unsigned short* l) {
    __builtin_amdgcn_global_load_lds(
        (const __attribute__((address_space(1))) unsigned int*)g,
        (__attribute__((address_space(3))) unsigned int*)l, 16, 0, 0);
}

// ---------------------------------------------------------------------------
// NT GEMM: C[m,n] = sum_k A[m,k] * B[n,k]   (bf16 in, f32 acc, bf16 out)
// 128x128 tile, BK=32, unpadded LDS (global_load_lds staging), m97-style.
// MODE 0: plain batched NT, bf16 store (used for MT prep and t = X.M)
// MODE 1: scores (adj = sigmoid(S*scale)*pm_n*pm_m; writes adjT bf16 [m][n];
//         accumulates deg/l0/c/g)
// MODE 2: aggregation (epilogue: *= deg2dis(deg[row]), bf16 store)
// ---------------------------------------------------------------------------
template <int MODE>
__global__ __launch_bounds__(256) void gemm_nt(
    const unsigned short* __restrict__ A0, const unsigned short* __restrict__ B0,
    unsigned short* __restrict__ C0,
    int K, int lda, int ldb, int ldc,
    long sA, long sB, long sC,
    const float* __restrict__ pmask, float* __restrict__ deg,
    unsigned short* __restrict__ adjT,
    float* __restrict__ l0_acc, float* __restrict__ c_acc, float* __restrict__ g_acc,
    int layer)
{
    __shared__ __align__(16) unsigned short As[128 * 32];
    __shared__ __align__(16) unsigned short Bs[128 * 32];
    __shared__ float pmr[128];
    __shared__ float pmc[128];

    const int tid  = threadIdx.x;
    const int lane = tid & 63;
    const int wave = tid >> 6;
    const int wr = (wave >> 1) << 6;
    const int wc = (wave & 1) << 6;
    const int z = blockIdx.z;
    const int rows0 = blockIdx.x << 7;
    const int cols0 = blockIdx.y << 7;

    const unsigned short* A = A0 + (size_t)z * sA + (size_t)rows0 * lda;
    const unsigned short* Bsrc = B0 + (size_t)z * sB + (size_t)cols0 * ldb;

    f32x4 acc[4][4] = {};

    // staging map: thread t -> row = wave*16 + (lane>>2), colblock = lane&3 (8 elems)
    const int srow = wave * 16 + (lane >> 2);
    const int scb  = (lane & 3) << 3;
    const unsigned short* Ag = A + (size_t)srow * lda + scb;
    const unsigned short* Bg = Bsrc + (size_t)srow * ldb + scb;
    unsigned short* lA0 = &As[wave * 512];
    unsigned short* lA1 = &As[2048 + wave * 512];
    unsigned short* lB0 = &Bs[wave * 512];
    unsigned short* lB1 = &Bs[2048 + wave * 512];
    const size_t a64 = (size_t)64 * lda, b64 = (size_t)64 * ldb;

    const int mrow = lane & 15;
    const int kq   = (lane >> 4) << 3;

    for (int kt = 0; kt < K; kt += 32) {
        __syncthreads();
        gload16(Ag + kt, lA0);
        gload16(Ag + a64 + kt, lA1);
        gload16(Bg + kt, lB0);
        gload16(Bg + b64 + kt, lB1);
        __syncthreads();

        s16x8 af[4], bfr[4];
        #pragma unroll
        for (int i = 0; i < 4; ++i) {
            af[i]  = *(const s16x8*)(&As[(wr + i * 16 + mrow) * 32 + kq]);
            bfr[i] = *(const s16x8*)(&Bs[(wc + i * 16 + mrow) * 32 + kq]);
        }
        #pragma unroll
        for (int i = 0; i < 4; ++i)
            #pragma unroll
            for (int j = 0; j < 4; ++j)
                acc[i][j] = __builtin_amdgcn_mfma_f32_16x16x32_bf16(af[i], bfr[j], acc[i][j], 0, 0, 0);
    }

    const int colb = lane & 15, quad = lane >> 4;

    if constexpr (MODE != 1) {
        unsigned short* C = C0 + (size_t)z * sC;
        #pragma unroll
        for (int i = 0; i < 4; ++i) {
            const int rbase = rows0 + wr + i * 16 + (quad << 2);
            float dv[4];
            if constexpr (MODE == 2) {
                #pragma unroll
                for (int r = 0; r < 4; ++r) dv[r] = deg2dis(deg[(size_t)z * NODES + rbase + r]);
            }
            #pragma unroll
            for (int j = 0; j < 4; ++j) {
                const int cc = cols0 + wc + j * 16 + colb;
                #pragma unroll
                for (int r = 0; r < 4; ++r) {
                    float v = acc[i][j][r];
                    if constexpr (MODE == 2) v *= dv[r];
                    C[(size_t)(rbase + r) * ldc + cc] = f2bf(v);
                }
            }
        }
    } else {
        __syncthreads();
        if (tid < 128) pmr[tid] = pmask[(size_t)z * NODES + rows0 + tid];
        else if (tid < 256) pmc[tid - 128] = pmask[(size_t)z * NODES + cols0 + (tid - 128)];
        __syncthreads();

        float tot = 0.f, gs = 0.f, cs = 0.f;
        #pragma unroll
        for (int i = 0; i < 4; ++i) {
            const int nloc = wr + i * 16 + (quad << 2);
            #pragma unroll
            for (int r = 0; r < 4; ++r) {
                const int n = rows0 + nloc + r;
                const float pmn = pmr[nloc + r];
                float dp = 0.f;
                #pragma unroll
                for (int j = 0; j < 4; ++j) {
                    const int mloc = wc + j * 16 + colb;
                    const int m = cols0 + mloc;
                    float a = pmn * pmc[mloc] * sigm(acc[i][j][r] * QK_SCALE);
                    acc[i][j][r] = a;
                    dp += a;
                    tot += a;
                    if (m < NODES - 1) {
                        if (n < NODES - 1) gs += a;
                        else cs += a;
                    }
                }
                dp += __shfl_xor(dp, 1, 16);
                dp += __shfl_xor(dp, 2, 16);
                dp += __shfl_xor(dp, 4, 16);
                dp += __shfl_xor(dp, 8, 16);
                if (colb == 0) atomicAdd(&deg[(size_t)z * NODES + n], dp);
            }
        }
        // adj^T (bf16, [b][m][n]) into this layer's slice (also feeds agg GEMM)
        #pragma unroll
        for (int i = 0; i < 4; ++i) {
            const int nb = rows0 + wr + i * 16 + (quad << 2);
            #pragma unroll
            for (int j = 0; j < 4; ++j) {
                const int m = cols0 + wc + j * 16 + colb;
                ushort4 pk;
                pk.x = f2bf(acc[i][j][0]); pk.y = f2bf(acc[i][j][1]);
                pk.z = f2bf(acc[i][j][2]); pk.w = f2bf(acc[i][j][3]);
                *(ushort4*)(adjT + ((size_t)z * NODES + m) * NODES + nb) = pk;
            }
        }
        #pragma unroll
        for (int o = 1; o < 64; o <<= 1) {
            tot += __shfl_xor(tot, o, 64);
            gs  += __shfl_xor(gs, o, 64);
            cs  += __shfl_xor(cs, o, 64);
        }
        if (lane == 0) {
            atomicAdd(l0_acc, tot);
            atomicAdd(&g_acc[z * LAYERS + layer], gs);
            atomicAdd(&c_acc[z * LAYERS + layer], cs);
        }
    }
}

// ---------------------------------------------------------------------------
// adjs[b][n][m][l] = f32(adjT[l][b][m][n])  — LDS-transposed, coalesced stores
// ---------------------------------------------------------------------------
__global__ __launch_bounds__(256) void interleave_adjs(
    const unsigned short* __restrict__ adjT, float* __restrict__ adjs)
{
    __shared__ unsigned short t[4][32][36];
    const int b = blockIdx.z, m0 = blockIdx.x << 5, n0 = blockIdx.y << 5;
    const int tr = threadIdx.x >> 3, tc = (threadIdx.x & 7) << 2;
    #pragma unroll
    for (int l = 0; l < LAYERS; ++l) {
        ushort4 v = *(const ushort4*)(adjT + (((size_t)l * BATCH + b) * NODES + m0 + tr) * NODES + n0 + tc);
        t[l][tr][tc] = v.x; t[l][tr][tc + 1] = v.y; t[l][tr][tc + 2] = v.z; t[l][tr][tc + 3] = v.w;
    }
    __syncthreads();
    float* dst = adjs + (((size_t)b * NODES + n0 + tr) * NODES + m0 + tc) * LAYERS;
    #pragma unroll
    for (int mm = 0; mm < 4; ++mm) {
        float4 f;
        f.x = bf2f(t[0][tc + mm][tr]); f.y = bf2f(t[1][tc + mm][tr]);
        f.z = bf2f(t[2][tc + mm][tr]); f.w = bf2f(t[3][tc + mm][tr]);
        *(float4*)(dst + mm * 4) = f;
    }
}

// ---------------------------------------------------------------------------
// fp_t[b][d][n] = bf16(deg2dis(deg[b][n]) * X[b][n][d])   (X bf16)
// ---------------------------------------------------------------------------
__global__ void fp_transpose(const unsigned short* __restrict__ X, const float* __restrict__ deg,
                             unsigned short* __restrict__ fpt)
{
    __shared__ unsigned short t[32][36];
    const int b = blockIdx.z;
    const int n0 = blockIdx.x << 5, d0 = blockIdx.y << 5;
    const int tr = threadIdx.x >> 3, tc = (threadIdx.x & 7) << 2;
    const float dv = deg2dis(deg[(size_t)b * NODES + n0 + tr]);
    ushort4 v = *(const ushort4*)(X + ((size_t)b * NODES + n0 + tr) * DIM + d0 + tc);
    t[tr][tc]     = f2bf(bf2f(v.x) * dv);
    t[tr][tc + 1] = f2bf(bf2f(v.y) * dv);
    t[tr][tc + 2] = f2bf(bf2f(v.z) * dv);
    t[tr][tc + 3] = f2bf(bf2f(v.w) * dv);
    __syncthreads();
    ushort4 o;
    o.x = t[tc + 0][tr]; o.y = t[tc + 1][tr]; o.z = t[tc + 2][tr]; o.w = t[tc + 3][tr];
    *(ushort4*)(fpt + ((size_t)b * DIM + d0 + tr) * NODES + n0 + tc) = o;
}

// ---------------------------------------------------------------------------
// Combined f32->bf16 cast: feat (12288 blk), Wq (2304 blk), Wk (2304 blk)
// ---------------------------------------------------------------------------
__global__ void cast_all(const float* __restrict__ feat, const float* __restrict__ Wq,
                         const float* __restrict__ Wk, unsigned short* __restrict__ featb,
                         unsigned short* __restrict__ Wqb, unsigned short* __restrict__ Wkb)
{
    const int bx = blockIdx.x;
    const float* src; unsigned short* dst; size_t base;
    if (bx < 12288)      { src = feat; dst = featb; base = (size_t)bx * 1024; }
    else if (bx < 14592) { src = Wq;   dst = Wqb;   base = (size_t)(bx - 12288) * 1024; }
    else                 { src = Wk;   dst = Wkb;   base = (size_t)(bx - 14592) * 1024; }
    const size_t i = base + ((size_t)threadIdx.x << 2);
    float4 v = *(const float4*)(src + i);
    *(ushort4*)(dst + i) = pk4(v);
}

__global__ void psum_kernel(const float* __restrict__ pm, float* __restrict__ ps)
{
    const int b = blockIdx.x, t = threadIdx.x;
    float s = pm[(size_t)b * NODES + t] + pm[(size_t)b * NODES + 256 + t];
    #pragma unroll
    for (int o = 1; o < 64; o <<= 1) s += __shfl_xor(s, o, 64);
    __shared__ float sh[4];
    if ((t & 63) == 0) sh[t >> 6] = s;
    __syncthreads();
    if (t == 0) ps[b] = sh[0] + sh[1] + sh[2] + sh[3];
}

// ---------------------------------------------------------------------------
// Final fused output: all 5 preds in one pass. One wave per (b,n) row.
// Also (block 0) finalizes c/g sparsity and l0 scalar.
// ---------------------------------------------------------------------------
__global__ __launch_bounds__(256) void final_out(
    const float* __restrict__ X0f, const unsigned short* __restrict__ X1,
    const unsigned short* __restrict__ X2, const unsigned short* __restrict__ X3,
    const unsigned short* __restrict__ X4,
    const float* __restrict__ pw, const float* __restrict__ pb,
    const float* __restrict__ ps, const float* __restrict__ c_acc,
    const float* __restrict__ g_acc, const float* __restrict__ l0,
    float* __restrict__ ob)
{
    if (blockIdx.x == 0) {
        const int t = threadIdx.x;
        if (t < BATCH * LAYERS) {
            const int b = t >> 2;
            const float p = ps[b];
            ob[C_OFF + t] = c_acc[t] / p;
            ob[G_OFF + t] = g_acc[t] / (p * p);
        }
        if (t == 0) {
            float fs = 1e-8f;
            for (int b = 0; b < BATCH; ++b) fs += ps[b] * ps[b];
            ob[L0_OFF] = l0[0] / (fs * (float)LAYERS);
        }
    }

    const int row = (blockIdx.x << 2) + (threadIdx.x >> 6);
    const int lane = threadIdx.x & 63;
    const unsigned short* Xb[4] = { X1 + (size_t)row * DIM, X2 + (size_t)row * DIM,
                                    X3 + (size_t)row * DIM, X4 + (size_t)row * DIM };
    float xs[5][12];
    float dot[5] = {};
    #pragma unroll
    for (int c = 0; c < 3; ++c) {
        const int idx = c * 256 + (lane << 2);
        float4 wv = *(const float4*)(pw + idx);
        float4 x0 = *(const float4*)(X0f + (size_t)row * DIM + idx);
        xs[0][c * 4 + 0] = x0.x; xs[0][c * 4 + 1] = x0.y;
        xs[0][c * 4 + 2] = x0.z; xs[0][c * 4 + 3] = x0.w;
        dot[0] += x0.x * wv.x + x0.y * wv.y + x0.z * wv.z + x0.w * wv.w;
        #pragma unroll
        for (int l = 0; l < 4; ++l) {
            ushort4 xv = *(const ushort4*)(Xb[l] + idx);
            float a0 = bf2f(xv.x), a1 = bf2f(xv.y), a2 = bf2f(xv.z), a3 = bf2f(xv.w);
            xs[l + 1][c * 4 + 0] = a0; xs[l + 1][c * 4 + 1] = a1;
            xs[l + 1][c * 4 + 2] = a2; xs[l + 1][c * 4 + 3] = a3;
            dot[l + 1] += a0 * wv.x + a1 * wv.y + a2 * wv.z + a3 * wv.w;
        }
    }
    #pragma unroll
    for (int l = 0; l < 5; ++l)
        #pragma unroll
        for (int o = 1; o < 64; o <<= 1) dot[l] += __shfl_xor(dot[l], o, 64);
    const float pbv = pb[0];
    float r[5];
    #pragma unroll
    for (int l = 0; l < 5; ++l) r[l] = sigm(dot[l] + pbv);
    if (lane == 0) {
        float* rr = ob + RET_OFF + (size_t)row * (LAYERS + 1);
        rr[0] = r[0]; rr[1] = r[1]; rr[2] = r[2]; rr[3] = r[3]; rr[4] = r[4];
    }
    float* orow = ob + OUT_OFF + (size_t)row * DIM;
    #pragma unroll
    for (int c = 0; c < 3; ++c) {
        float4 p;
        p.x = r[0] * xs[0][c * 4 + 0]; p.y = r[0] * xs[0][c * 4 + 1];
        p.z = r[0] * xs[0][c * 4 + 2]; p.w = r[0] * xs[0][c * 4 + 3];
        #pragma unroll
        for (int l = 1; l < 5; ++l) {
            p.x += r[l] * xs[l][c * 4 + 0]; p.y += r[l] * xs[l][c * 4 + 1];
            p.z += r[l] * xs[l][c * 4 + 2]; p.w += r[l] * xs[l][c * 4 + 3];
        }
        *(float4*)(orow + c * 256 + (lane << 2)) = p;
    }
}

// ---------------------------------------------------------------------------
extern "C" void kernel_launch(void* const* d_in, const int* in_sizes, int n_in,
                              void* d_out, int out_size, void* d_ws, size_t ws_size,
                              hipStream_t stream)
{
    (void)in_sizes; (void)n_in; (void)out_size; (void)ws_size;
    const float* pmask = (const float*)d_in[0];
    const float* feat  = (const float*)d_in[1];
    const float* Wq    = (const float*)d_in[2];
    const float* Wk    = (const float*)d_in[3];
    const float* projw = (const float*)d_in[4];
    const float* projb = (const float*)d_in[5];
    float* ob = (float*)d_out;

    char* w = (char*)d_ws;
    unsigned short* Xb[4];                                     // bf16 [B,N,D] per layer
    Xb[0] = (unsigned short*)(w + 0);
    Xb[1] = (unsigned short*)(w + 25165824);
    Xb[2] = (unsigned short*)(w + 50331648);
    Xb[3] = (unsigned short*)(w + 75497472);
    unsigned short* qws   = (unsigned short*)(w + 100663296);  //  25165824 B bf16 t / fp_t
    unsigned short* featb = (unsigned short*)(w + 125829120);  //  25165824 B bf16 feat
    unsigned short* adjT  = (unsigned short*)(w + 150994944);  //  67108864 B bf16 [L,B,m,n]
    unsigned short* Wqb   = (unsigned short*)(w + 218103808);  //   4718592 B bf16 [L,D,D]
    unsigned short* Wkb   = (unsigned short*)(w + 222822400);  //   4718592 B bf16 [L,D,D]
    unsigned short* MT    = (unsigned short*)(w + 227540992);  //   4718592 B bf16 [L,D,D]  MT[l][j][i]
    float* deg_all = (float*)(w + 232259584);                  //    262144 B f32 [L,B,N]
    float* c_acc   = (float*)(w + 232521728);                  //       512 B
    float* g_acc   = (float*)(w + 232522240);                  //       512 B
    float* l0_acc  = (float*)(w + 232522752);                  //       256 B
    float* p_sum   = (float*)(w + 232523008);                  //       256 B

    dim3 blk(256);
    hipMemsetAsync(w + 232259584, 0, 263680, stream);  // deg_all + c_acc + g_acc + l0_acc

    cast_all<<<dim3(16896), blk, 0, stream>>>(feat, Wq, Wk, featb, Wqb, Wkb);
    psum_kernel<<<dim3(32), blk, 0, stream>>>(pmask, p_sum);

    // MT[l] = Wk[l] @ Wq[l]^T  (NT, batched over layers): MT[j][i] = sum_e Wk[j][e]Wq[i][e]
    gemm_nt<0><<<dim3(6, 6, 4), blk, 0, stream>>>(
        Wkb, Wqb, MT, DIM, DIM, DIM, DIM,
        (long)DIM * DIM, (long)DIM * DIM, (long)DIM * DIM,
        nullptr, nullptr, nullptr, nullptr, nullptr, nullptr, 0);

    for (int l = 0; l < LAYERS; ++l) {
        float* deg_l = deg_all + (size_t)l * BATCH * NODES;
        unsigned short* adjT_l = adjT + (size_t)l * BATCH * NODES * NODES;
        const unsigned short* Xsrc = (l == 0) ? featb : Xb[l - 1];

        // t = X @ M[l]   (t[n][j] = sum_i X[n][i] MT[j][i])
        gemm_nt<0><<<dim3(128, 6, 1), blk, 0, stream>>>(
            Xsrc, MT + (size_t)l * DIM * DIM, qws,
            DIM, DIM, DIM, DIM, 0L, 0L, 0L,
            nullptr, nullptr, nullptr, nullptr, nullptr, nullptr, 0);

        // S = t @ X^T (batched) + sigmoid/mask/stats epilogue, writes adjT_l
        gemm_nt<1><<<dim3(4, 4, 32), blk, 0, stream>>>(
            qws, Xsrc, nullptr,
            DIM, DIM, DIM, 0, (long)NODES * DIM, (long)NODES * DIM, 0L,
            pmask, deg_l, adjT_l, l0_acc, c_acc, g_acc, l);

        fp_transpose<<<dim3(16, 24, 32), blk, 0, stream>>>(Xsrc, deg_l, qws);

        // X' = dis[m] * (adjT_l @ (dis[n]*X))  (batched)
        gemm_nt<2><<<dim3(4, 6, 32), blk, 0, stream>>>(
            adjT_l, qws, Xb[l],
            NODES, NODES, NODES, DIM, (long)NODES * NODES, (long)DIM * NODES, (long)NODES * DIM,
            nullptr, deg_l, nullptr, nullptr, nullptr, nullptr, 0);
    }

    interleave_adjs<<<dim3(16, 16, 32), blk, 0, stream>>>(adjT, ob + ADJS_OFF);
    final_out<<<dim3(4096), blk, 0, stream>>>(feat, Xb[0], Xb[1], Xb[2], Xb[3],
                                              projw, projb, p_sum, c_acc, g_acc, l0_acc, ob);
}